// Round 1
// baseline (45167.239 us; speedup 1.0000x reference)
//
#include <hip/hip_runtime.h>
#include <cstddef>
#include <cstdint>

// ---------------------------------------------------------------------------
// BehaviorModel GRU seq2seq: 64 enc steps + 512 dec steps (64 teacher + 448 AR)
// B=512 samples, H=256, K=128, L=2.
// Partition: 32 clusters x 16 samples; 8 WGs per cluster, 32 hidden units each.
// 2 intra-cluster barriers per step; proj fused via Wfused = Wih0 @ outW.
// ---------------------------------------------------------------------------

// ws layout (float offsets)
static const size_t OFF_H0A = 0;                    // 512*256
static const size_t OFF_H1A = 131072;               // 512*256
static const size_t OFF_H0B = 262144;
static const size_t OFF_H1B = 393216;
static const size_t OFF_WF  = 524288;               // 768*256 = 196608
static const size_t OFF_BF  = OFF_WF + 196608;      // 768 (pad to 1024)
static const size_t OFF_CTR = OFF_BF + 1024;        // 32*64 uints

#define SIGF(x) (1.0f / (1.0f + __expf(-(x))))

__device__ __forceinline__ float agent_ld(const float* p) {
    return __hip_atomic_load(p, __ATOMIC_RELAXED, __HIP_MEMORY_SCOPE_AGENT);
}
__device__ __forceinline__ void agent_st(float* p, float v) {
    __hip_atomic_store(p, v, __ATOMIC_RELAXED, __HIP_MEMORY_SCOPE_AGENT);
}

// Precompute fused L0 input weights for the autoregressive phase:
// Wf[r][h] = sum_k dec_Wih0[r][k] * outW[k][h];  bf[r] = dec_Wih0[r]·out_b + dec_bih0[r]
__global__ void fuse_wb(const float* __restrict__ Wih0, const float* __restrict__ oW,
                        const float* __restrict__ ob, const float* __restrict__ bih0,
                        float* __restrict__ Wf, float* __restrict__ bf) {
    int idx = blockIdx.x * 256 + threadIdx.x;   // 768*256 elements
    int r = idx >> 8, h = idx & 255;
    const float* wr = Wih0 + (size_t)r * 128;
    float a = 0.f;
    for (int k = 0; k < 128; ++k) a = fmaf(wr[k], oW[(size_t)k * 256 + h], a);
    Wf[idx] = a;
    if (h == 0) {
        float b = 0.f;
        for (int k = 0; k < 128; ++k) b = fmaf(wr[k], ob[k], b);
        bf[r] = b + bih0[r];
    }
}

// One GRU layer phase for this WG's 96 gate rows x 16 samples.
// Thread (r16 = tid>>4, s = tid&15) computes 6 gate rows (2 units x 3 gates)
// for sample s. srcI = LDS row &bufI[s][0] (K=KI), srcH = LDS row &bufH[s][0]
// (K=256, also h_prev). Writes h_new (agent-scope) to hout.
template<int KI>
__device__ __forceinline__ void gru_phase(
    const float* __restrict__ Wi, const float* __restrict__ Wh,
    const float* __restrict__ bi, const float* __restrict__ bh,
    const float* srcI, const float* srcH,
    float* hout, int s0, int s, int j0, int r16)
{
    float ai[6], ah[6];
    const float* wi[6]; const float* wh[6]; int grow[6];
    #pragma unroll
    for (int it = 0; it < 6; ++it) {
        ai[it] = 0.f; ah[it] = 0.f;
        int ul = r16 + ((it & 1) << 4);           // unit_local in [0,32)
        int r = ((it >> 1) << 8) + j0 + ul;       // gate*256 + j0 + ul
        grow[it] = r;
        wi[it] = Wi + (size_t)r * KI;
        wh[it] = Wh + (size_t)r * 256;
    }
    #pragma unroll 2
    for (int k4 = 0; k4 < (KI >> 2); ++k4) {
        float4 xv = *(const float4*)(srcI + (k4 << 2));
        #pragma unroll
        for (int it = 0; it < 6; ++it) {
            float4 w = *(const float4*)(wi[it] + (k4 << 2));
            ai[it] = fmaf(w.x, xv.x, ai[it]);
            ai[it] = fmaf(w.y, xv.y, ai[it]);
            ai[it] = fmaf(w.z, xv.z, ai[it]);
            ai[it] = fmaf(w.w, xv.w, ai[it]);
        }
    }
    #pragma unroll 2
    for (int k4 = 0; k4 < 64; ++k4) {
        float4 hv = *(const float4*)(srcH + (k4 << 2));
        #pragma unroll
        for (int it = 0; it < 6; ++it) {
            float4 w = *(const float4*)(wh[it] + (k4 << 2));
            ah[it] = fmaf(w.x, hv.x, ah[it]);
            ah[it] = fmaf(w.y, hv.y, ah[it]);
            ah[it] = fmaf(w.z, hv.z, ah[it]);
            ah[it] = fmaf(w.w, hv.w, ah[it]);
        }
    }
    #pragma unroll
    for (int a = 0; a < 2; ++a) {
        float gr = ai[a]     + bi[grow[a]]     + ah[a]     + bh[grow[a]];
        float gz = ai[2 + a] + bi[grow[2 + a]] + ah[2 + a] + bh[grow[2 + a]];
        float rr = SIGF(gr);
        float zz = SIGF(gz);
        float nn = tanhf(ai[4 + a] + bi[grow[4 + a]] + rr * (ah[4 + a] + bh[grow[4 + a]]));
        int j = j0 + r16 + (a << 4);
        float hp = srcH[j];
        agent_st(hout + (size_t)(s0 + s) * 256 + j, (1.f - zz) * nn + zz * hp);
    }
}

__global__ __launch_bounds__(256, 1) void behav_main(
    const float* __restrict__ pose,
    const float* __restrict__ eW0i, const float* __restrict__ eW0h,
    const float* __restrict__ eb0i, const float* __restrict__ eb0h,
    const float* __restrict__ eW1i, const float* __restrict__ eW1h,
    const float* __restrict__ eb1i, const float* __restrict__ eb1h,
    const float* __restrict__ dW0i, const float* __restrict__ dW0h,
    const float* __restrict__ db0i, const float* __restrict__ db0h,
    const float* __restrict__ dW1i, const float* __restrict__ dW1h,
    const float* __restrict__ db1i, const float* __restrict__ db1h,
    const float* __restrict__ oW, const float* __restrict__ ob,
    float* __restrict__ out,
    float* h0a, float* h0b, float* h1a, float* h1b,
    const float* __restrict__ Wf, const float* __restrict__ bf,
    unsigned* ctrs)
{
    __shared__ float xls[16][132];    // staged x (K=128), padded
    __shared__ float h0ls[16][260];   // staged h0 (256), padded
    __shared__ float h1ls[16][260];   // staged h1 (256), padded

    const int tid = threadIdx.x;
    const int bid = blockIdx.x;
    const int c = bid >> 3, u = bid & 7;     // cluster, unit-group
    const int s0 = c << 4, j0 = u << 5;      // sample base, unit base
    const int r16 = tid >> 4, s = tid & 15;
    unsigned* ctr = ctrs + (c << 6);
    unsigned epoch = 0;

    float* h0buf[2] = { h0a, h0b };
    float* h1buf[2] = { h1a, h1b };
    int pp = 0;

    // Intra-cluster barrier (8 WGs). Fence-free: all shared state uses
    // agent-scope atomics; __syncthreads drains vmcnt before the arrive-add.
    auto cbar = [&]() {
        __syncthreads();
        ++epoch;
        if (tid == 0) {
            __hip_atomic_fetch_add(ctr, 1u, __ATOMIC_RELAXED, __HIP_MEMORY_SCOPE_AGENT);
            unsigned tgt = epoch * 8u;
            while (__hip_atomic_load(ctr, __ATOMIC_RELAXED, __HIP_MEMORY_SCOPE_AGENT) < tgt)
                __builtin_amdgcn_s_sleep(1);
        }
        __syncthreads();
    };

    auto stage_x = [&](int t) {
        #pragma unroll
        for (int i = 0; i < 2; ++i) {
            int idx = tid + (i << 8);               // 512 float4 chunks
            int ss = idx >> 5, kq = idx & 31;
            float4 v = *(const float4*)(pose + (size_t)(s0 + ss) * 8192 + (size_t)t * 128 + (kq << 2));
            *(float4*)&xls[ss][kq << 2] = v;
        }
    };
    auto stage_h = [&](float (*dst)[260], const float* src) {
        #pragma unroll
        for (int i = 0; i < 16; ++i) {
            dst[i][tid] = agent_ld(src + (size_t)(s0 + i) * 256 + tid);
        }
    };
    auto do_proj = [&](int tprev) {
        int pl = tid >> 4, ss = tid & 15;
        int p = (u << 4) + pl;
        const float* wr = oW + (size_t)p * 256;
        const float* hr = &h1ls[ss][0];
        float acc = 0.f;
        #pragma unroll 4
        for (int k4 = 0; k4 < 64; ++k4) {
            float4 hv = *(const float4*)(hr + (k4 << 2));
            float4 w  = *(const float4*)(wr + (k4 << 2));
            acc = fmaf(w.x, hv.x, acc); acc = fmaf(w.y, hv.y, acc);
            acc = fmaf(w.z, hv.z, acc); acc = fmaf(w.w, hv.w, acc);
        }
        out[(size_t)(s0 + ss) * 65536 + (size_t)tprev * 128 + p] = acc + ob[p];
    };

    // ===================== ENCODER: 64 steps =====================
    for (int t = 0; t < 64; ++t) {
        stage_x(t);
        stage_h(h0ls, h0buf[pp]);
        __syncthreads();
        gru_phase<128>(eW0i, eW0h, eb0i, eb0h, &xls[s][0], &h0ls[s][0],
                       h0buf[pp ^ 1], s0, s, j0, r16);
        cbar();
        stage_h(h0ls, h0buf[pp ^ 1]);
        stage_h(h1ls, h1buf[pp]);
        __syncthreads();
        gru_phase<256>(eW1i, eW1h, eb1i, eb1h, &h0ls[s][0], &h1ls[s][0],
                       h1buf[pp ^ 1], s0, s, j0, r16);
        cbar();
        pp ^= 1;
    }

    // ===================== DECODER: 512 steps =====================
    for (int t = 0; t < 512; ++t) {
        const bool teacher = (t < 64);
        if (teacher) stage_x(t);
        stage_h(h0ls, h0buf[pp]);
        stage_h(h1ls, h1buf[pp]);       // h1_{t-1}: for proj (t>=1) and fused gi (t>=64)
        __syncthreads();
        if (t >= 1) do_proj(t - 1);     // out_{t-1} = outW·h1_{t-1} + ob
        if (teacher)
            gru_phase<128>(dW0i, dW0h, db0i, db0h, &xls[s][0], &h0ls[s][0],
                           h0buf[pp ^ 1], s0, s, j0, r16);
        else
            gru_phase<256>(Wf, dW0h, bf, db0h, &h1ls[s][0], &h0ls[s][0],
                           h0buf[pp ^ 1], s0, s, j0, r16);
        cbar();
        stage_h(h0ls, h0buf[pp ^ 1]);   // new h0; h1ls still holds h1_{t-1}
        __syncthreads();
        gru_phase<256>(dW1i, dW1h, db1i, db1h, &h0ls[s][0], &h1ls[s][0],
                       h1buf[pp ^ 1], s0, s, j0, r16);
        cbar();
        pp ^= 1;
    }

    // final projection: out_511 from h1_511
    stage_h(h1ls, h1buf[pp]);
    __syncthreads();
    do_proj(511);
}

extern "C" void kernel_launch(void* const* d_in, const int* in_sizes, int n_in,
                              void* d_out, int out_size, void* d_ws, size_t ws_size,
                              hipStream_t stream) {
    (void)in_sizes; (void)n_in; (void)out_size; (void)ws_size;

    const float* pose = (const float*)d_in[0];
    const float* eW0i = (const float*)d_in[1];
    const float* eW0h = (const float*)d_in[2];
    const float* eb0i = (const float*)d_in[3];
    const float* eb0h = (const float*)d_in[4];
    const float* eW1i = (const float*)d_in[5];
    const float* eW1h = (const float*)d_in[6];
    const float* eb1i = (const float*)d_in[7];
    const float* eb1h = (const float*)d_in[8];
    const float* dW0i = (const float*)d_in[9];
    const float* dW0h = (const float*)d_in[10];
    const float* db0i = (const float*)d_in[11];
    const float* db0h = (const float*)d_in[12];
    const float* dW1i = (const float*)d_in[13];
    const float* dW1h = (const float*)d_in[14];
    const float* db1i = (const float*)d_in[15];
    const float* db1h = (const float*)d_in[16];
    const float* oW   = (const float*)d_in[17];
    const float* ob   = (const float*)d_in[18];

    float* ws = (float*)d_ws;
    float* h0a = ws + OFF_H0A;
    float* h0b = ws + OFF_H0B;
    float* h1a = ws + OFF_H1A;
    float* h1b = ws + OFF_H1B;
    float* Wf  = ws + OFF_WF;
    float* bf  = ws + OFF_BF;
    unsigned* ctrs = (unsigned*)(ws + OFF_CTR);
    float* outf = (float*)d_out;

    // zero initial h (h0a+h1a are contiguous) and barrier counters
    hipMemsetAsync(d_ws, 0, 262144 * sizeof(float), stream);
    hipMemsetAsync((void*)ctrs, 0, 32 * 64 * sizeof(unsigned), stream);

    fuse_wb<<<dim3(768), dim3(256), 0, stream>>>(dW0i, oW, ob, db0i, Wf, bf);

    void* kargs[] = {
        (void*)&pose,
        (void*)&eW0i, (void*)&eW0h, (void*)&eb0i, (void*)&eb0h,
        (void*)&eW1i, (void*)&eW1h, (void*)&eb1i, (void*)&eb1h,
        (void*)&dW0i, (void*)&dW0h, (void*)&db0i, (void*)&db0h,
        (void*)&dW1i, (void*)&dW1h, (void*)&db1i, (void*)&db1h,
        (void*)&oW, (void*)&ob,
        (void*)&outf,
        (void*)&h0a, (void*)&h0b, (void*)&h1a, (void*)&h1b,
        (void*)&Wf, (void*)&bf,
        (void*)&ctrs
    };
    hipLaunchCooperativeKernel((const void*)behav_main, dim3(256), dim3(256),
                               kargs, 0, stream);
}

// Round 3
// 30622.897 us; speedup vs baseline: 1.4749x; 1.4749x over previous
//
#include <hip/hip_runtime.h>
#include <cstddef>
#include <cstdint>

// ---------------------------------------------------------------------------
// BehaviorModel GRU seq2seq: 64 enc steps + 512 dec steps (64 teacher + 448 AR)
// B=512, H=256, K=128, L=2.
// Partition: 32 clusters x 16 samples; 8 WGs per cluster (32 units each),
// WG = 512 threads (thread = 1 unit x 1 sample). Grid = 256 WGs = 1 WG/CU
// (8 waves/CU), cooperative launch (proven-launchable shape).
// XCD-aware mapping: all 8 WGs of a cluster share one XCD -> phase weights
// stay resident in that XCD's 4MB L2 (all clusters read the SAME weights).
// ---------------------------------------------------------------------------

static const size_t OFF_H0A = 0;                    // 512*256
static const size_t OFF_H1A = 131072;
static const size_t OFF_H0B = 262144;
static const size_t OFF_H1B = 393216;
static const size_t OFF_WF  = 524288;               // 768*256
static const size_t OFF_BF  = OFF_WF + 196608;      // 768 (pad 1024)
static const size_t OFF_CTR = OFF_BF + 1024;        // 64*64 uints

#define SIGF(x) (1.0f / (1.0f + __expf(-(x))))

__device__ __forceinline__ float agent_ld(const float* p) {
    return __hip_atomic_load(p, __ATOMIC_RELAXED, __HIP_MEMORY_SCOPE_AGENT);
}
__device__ __forceinline__ void agent_st(float* p, float v) {
    __hip_atomic_store(p, v, __ATOMIC_RELAXED, __HIP_MEMORY_SCOPE_AGENT);
}

// Wf[r][h] = sum_k dec_Wih0[r][k] * outW[k][h];  bf[r] = dec_Wih0[r]·out_b + dec_bih0[r]
__global__ void fuse_wb(const float* __restrict__ Wih0, const float* __restrict__ oW,
                        const float* __restrict__ ob, const float* __restrict__ bih0,
                        float* __restrict__ Wf, float* __restrict__ bf) {
    int idx = blockIdx.x * 256 + threadIdx.x;
    int r = idx >> 8, h = idx & 255;
    const float* wr = Wih0 + (size_t)r * 128;
    float a = 0.f;
    for (int k = 0; k < 128; ++k) a = fmaf(wr[k], oW[(size_t)k * 256 + h], a);
    Wf[idx] = a;
    if (h == 0) {
        float b = 0.f;
        for (int k = 0; k < 128; ++k) b = fmaf(wr[k], ob[k], b);
        bf[r] = b + bih0[r];
    }
}

// One GRU layer phase: thread (rs = tid>>4, s = tid&15) computes the 3 gate
// rows of unit (j0+rs) for sample s. srcI: LDS row (K=KI); srcH: LDS row
// (K=256, also h_prev). Writes h_new (agent-scope) to hout.
template<int KI>
__device__ __forceinline__ void gru_phase(
    const float* __restrict__ Wi, const float* __restrict__ Wh,
    const float* __restrict__ bi, const float* __restrict__ bh,
    const float* srcI, const float* srcH,
    float* hout, int s0, int s, int j0, int rs)
{
    float ai[3], ah[3];
    const float* wi[3]; const float* wh[3]; int grow[3];
    #pragma unroll
    for (int g = 0; g < 3; ++g) {
        ai[g] = 0.f; ah[g] = 0.f;
        int r = (g << 8) + j0 + rs;
        grow[g] = r;
        wi[g] = Wi + (size_t)r * KI;
        wh[g] = Wh + (size_t)r * 256;
    }
    #pragma unroll 4
    for (int k4 = 0; k4 < (KI >> 2); ++k4) {
        float4 xv = *(const float4*)(srcI + (k4 << 2));
        #pragma unroll
        for (int g = 0; g < 3; ++g) {
            float4 w = *(const float4*)(wi[g] + (k4 << 2));
            ai[g] = fmaf(w.x, xv.x, ai[g]);
            ai[g] = fmaf(w.y, xv.y, ai[g]);
            ai[g] = fmaf(w.z, xv.z, ai[g]);
            ai[g] = fmaf(w.w, xv.w, ai[g]);
        }
    }
    #pragma unroll 4
    for (int k4 = 0; k4 < 64; ++k4) {
        float4 hv = *(const float4*)(srcH + (k4 << 2));
        #pragma unroll
        for (int g = 0; g < 3; ++g) {
            float4 w = *(const float4*)(wh[g] + (k4 << 2));
            ah[g] = fmaf(w.x, hv.x, ah[g]);
            ah[g] = fmaf(w.y, hv.y, ah[g]);
            ah[g] = fmaf(w.z, hv.z, ah[g]);
            ah[g] = fmaf(w.w, hv.w, ah[g]);
        }
    }
    float gr = ai[0] + bi[grow[0]] + ah[0] + bh[grow[0]];
    float gz = ai[1] + bi[grow[1]] + ah[1] + bh[grow[1]];
    float rr = SIGF(gr);
    float zz = SIGF(gz);
    float nn = tanhf(ai[2] + bi[grow[2]] + rr * (ah[2] + bh[grow[2]]));
    int j = j0 + rs;
    float hp = srcH[j];
    agent_st(hout + (size_t)(s0 + s) * 256 + j, (1.f - zz) * nn + zz * hp);
}

__global__ __launch_bounds__(512, 2) void behav_main(
    const float* __restrict__ pose,
    const float* __restrict__ eW0i, const float* __restrict__ eW0h,
    const float* __restrict__ eb0i, const float* __restrict__ eb0h,
    const float* __restrict__ eW1i, const float* __restrict__ eW1h,
    const float* __restrict__ eb1i, const float* __restrict__ eb1h,
    const float* __restrict__ dW0i, const float* __restrict__ dW0h,
    const float* __restrict__ db0i, const float* __restrict__ db0h,
    const float* __restrict__ dW1i, const float* __restrict__ dW1h,
    const float* __restrict__ db1i, const float* __restrict__ db1h,
    const float* __restrict__ oW, const float* __restrict__ ob,
    float* __restrict__ out,
    float* h0a, float* h0b, float* h1a, float* h1b,
    const float* __restrict__ Wf, const float* __restrict__ bf,
    unsigned* ctrs)
{
    __shared__ float xls[16][132];    // staged x (K=128), padded
    __shared__ float h0ls[16][260];   // staged h0 (256), padded
    __shared__ float h1ls[16][260];   // staged h1 (256), padded

    const int tid = threadIdx.x;
    const int bid = blockIdx.x;
    // XCD-aware decode: cluster c's 8 WGs all have bid % 8 == c % 8 -> one XCD.
    const int xcd = bid & 7;
    const int inner = bid >> 3;               // [0,32)
    const int u = inner & 7;                  // unit-group [0,8)
    const int c = ((inner >> 3) << 3) | xcd;  // cluster [0,32)
    const int s0 = c << 4, j0 = u << 5;
    const int rs = tid >> 4, s = tid & 15;
    unsigned* ctr = ctrs + (c << 6);
    unsigned epoch = 0;

    float* h0buf[2] = { h0a, h0b };
    float* h1buf[2] = { h1a, h1b };
    int pp = 0;

    // Intra-cluster barrier (8 WGs, all on one XCD). Fence-free: shared state
    // uses agent-scope atomics; __syncthreads drains vmcnt before arrive-add.
    auto cbar = [&]() {
        __syncthreads();
        ++epoch;
        if (tid == 0) {
            __hip_atomic_fetch_add(ctr, 1u, __ATOMIC_RELAXED, __HIP_MEMORY_SCOPE_AGENT);
            unsigned tgt = epoch * 8u;
            while (__hip_atomic_load(ctr, __ATOMIC_RELAXED, __HIP_MEMORY_SCOPE_AGENT) < tgt)
                __builtin_amdgcn_s_sleep(1);
        }
        __syncthreads();
    };

    auto stage_x = [&](int t) {
        int ss = tid >> 5, kq = tid & 31;     // 512 float4 chunks, one per thread
        float4 v = *(const float4*)(pose + (size_t)(s0 + ss) * 8192 + (size_t)t * 128 + (kq << 2));
        *(float4*)&xls[ss][kq << 2] = v;
    };
    auto stage_h = [&](float (*dst)[260], const float* src) {
        #pragma unroll
        for (int i = 0; i < 8; ++i) {
            int idx = (i << 9) | tid;         // 16*256 = 4096 floats
            int row = idx >> 8, col = idx & 255;
            dst[row][col] = agent_ld(src + (size_t)(s0 + row) * 256 + col);
        }
    };
    // out_{tprev} = outW · h1ls + ob ; K split in halves across thread pairs.
    auto do_proj = [&](int tprev) {
        int ss = tid & 15;
        int khalf = (tid >> 4) & 1;
        int pl = tid >> 5;                    // [0,16)
        int p = (u << 4) + pl;
        const float* wr = oW + (size_t)p * 256 + (khalf << 7);
        const float* hr = &h1ls[ss][khalf << 7];
        float acc = 0.f;
        #pragma unroll 4
        for (int k4 = 0; k4 < 32; ++k4) {
            float4 hv = *(const float4*)(hr + (k4 << 2));
            float4 w  = *(const float4*)(wr + (k4 << 2));
            acc = fmaf(w.x, hv.x, acc); acc = fmaf(w.y, hv.y, acc);
            acc = fmaf(w.z, hv.z, acc); acc = fmaf(w.w, hv.w, acc);
        }
        acc += __shfl_xor(acc, 16);           // combine the two K-halves
        if (khalf == 0)
            out[(size_t)(s0 + ss) * 65536 + (size_t)tprev * 128 + p] = acc + ob[p];
    };

    // ===================== ENCODER: 64 steps =====================
    for (int t = 0; t < 64; ++t) {
        stage_x(t);
        stage_h(h0ls, h0buf[pp]);
        __syncthreads();
        gru_phase<128>(eW0i, eW0h, eb0i, eb0h, &xls[s][0], &h0ls[s][0],
                       h0buf[pp ^ 1], s0, s, j0, rs);
        cbar();
        stage_h(h0ls, h0buf[pp ^ 1]);
        stage_h(h1ls, h1buf[pp]);
        __syncthreads();
        gru_phase<256>(eW1i, eW1h, eb1i, eb1h, &h0ls[s][0], &h1ls[s][0],
                       h1buf[pp ^ 1], s0, s, j0, rs);
        cbar();
        pp ^= 1;
    }

    // ===================== DECODER: 512 steps =====================
    for (int t = 0; t < 512; ++t) {
        const bool teacher = (t < 64);
        if (teacher) stage_x(t);
        stage_h(h0ls, h0buf[pp]);
        stage_h(h1ls, h1buf[pp]);       // h1_{t-1}: proj (t>=1) and fused gi (t>=64)
        __syncthreads();
        if (t >= 1) do_proj(t - 1);
        if (teacher)
            gru_phase<128>(dW0i, dW0h, db0i, db0h, &xls[s][0], &h0ls[s][0],
                           h0buf[pp ^ 1], s0, s, j0, rs);
        else
            gru_phase<256>(Wf, dW0h, bf, db0h, &h1ls[s][0], &h0ls[s][0],
                           h0buf[pp ^ 1], s0, s, j0, rs);
        cbar();
        stage_h(h0ls, h0buf[pp ^ 1]);   // new h0; h1ls still holds h1_{t-1}
        __syncthreads();
        gru_phase<256>(dW1i, dW1h, db1i, db1h, &h0ls[s][0], &h1ls[s][0],
                       h1buf[pp ^ 1], s0, s, j0, rs);
        cbar();
        pp ^= 1;
    }

    // final projection: out_511 from h1_511
    stage_h(h1ls, h1buf[pp]);
    __syncthreads();
    do_proj(511);
}

extern "C" void kernel_launch(void* const* d_in, const int* in_sizes, int n_in,
                              void* d_out, int out_size, void* d_ws, size_t ws_size,
                              hipStream_t stream) {
    (void)in_sizes; (void)n_in; (void)out_size; (void)ws_size;

    const float* pose = (const float*)d_in[0];
    const float* eW0i = (const float*)d_in[1];
    const float* eW0h = (const float*)d_in[2];
    const float* eb0i = (const float*)d_in[3];
    const float* eb0h = (const float*)d_in[4];
    const float* eW1i = (const float*)d_in[5];
    const float* eW1h = (const float*)d_in[6];
    const float* eb1i = (const float*)d_in[7];
    const float* eb1h = (const float*)d_in[8];
    const float* dW0i = (const float*)d_in[9];
    const float* dW0h = (const float*)d_in[10];
    const float* db0i = (const float*)d_in[11];
    const float* db0h = (const float*)d_in[12];
    const float* dW1i = (const float*)d_in[13];
    const float* dW1h = (const float*)d_in[14];
    const float* db1i = (const float*)d_in[15];
    const float* db1h = (const float*)d_in[16];
    const float* oW   = (const float*)d_in[17];
    const float* ob   = (const float*)d_in[18];

    float* ws = (float*)d_ws;
    float* h0a = ws + OFF_H0A;
    float* h0b = ws + OFF_H0B;
    float* h1a = ws + OFF_H1A;
    float* h1b = ws + OFF_H1B;
    float* Wf  = ws + OFF_WF;
    float* bf  = ws + OFF_BF;
    unsigned* ctrs = (unsigned*)(ws + OFF_CTR);
    float* outf = (float*)d_out;

    hipMemsetAsync(d_ws, 0, 262144 * sizeof(float), stream);   // h0a + h1a = 0
    hipMemsetAsync((void*)ctrs, 0, 64 * 64 * sizeof(unsigned), stream);

    fuse_wb<<<dim3(768), dim3(256), 0, stream>>>(dW0i, oW, ob, db0i, Wf, bf);

    void* kargs[] = {
        (void*)&pose,
        (void*)&eW0i, (void*)&eW0h, (void*)&eb0i, (void*)&eb0h,
        (void*)&eW1i, (void*)&eW1h, (void*)&eb1i, (void*)&eb1h,
        (void*)&dW0i, (void*)&dW0h, (void*)&db0i, (void*)&db0h,
        (void*)&dW1i, (void*)&dW1h, (void*)&db1i, (void*)&db1h,
        (void*)&oW, (void*)&ob,
        (void*)&outf,
        (void*)&h0a, (void*)&h0b, (void*)&h1a, (void*)&h1b,
        (void*)&Wf, (void*)&bf,
        (void*)&ctrs
    };
    hipLaunchCooperativeKernel((const void*)behav_main, dim3(256), dim3(512),
                               kargs, 0, stream);
}

// Round 4
// 13384.206 us; speedup vs baseline: 3.3747x; 2.2880x over previous
//
#include <hip/hip_runtime.h>
#include <cstddef>
#include <cstdint>

// ---------------------------------------------------------------------------
// BehaviorModel GRU seq2seq: 64 enc + 64 teacher + 448 AR steps.
// B=512, H=256, K=128, L=2.
// Partition: 32 clusters x 16 samples; 8 WGs/cluster (32 units each);
// WG = 512 thr, thread = (unit u, k-slice ks:16). Grid 256 coop (proven).
// KEY CHANGE vs r3: weights are REGISTER-STATIONARY (thread holds its
// 3x16-float K-slice of every live matrix; loaded once per era), acts are
// read from skewed LDS; K-reduction via DPP on the VALU pipe.
// ---------------------------------------------------------------------------

static const size_t OFF_H0A = 0;                    // 512*256
static const size_t OFF_H1A = 131072;
static const size_t OFF_H0B = 262144;
static const size_t OFF_H1B = 393216;
static const size_t OFF_WF  = 524288;               // 768*256
static const size_t OFF_BF  = OFF_WF + 196608;      // 768 (pad 1024)
static const size_t OFF_CTR = OFF_BF + 1024;        // 32*64 uints

#define SIGF(x) (1.0f / (1.0f + __expf(-(x))))

__device__ __forceinline__ float agent_ld(const float* p) {
    return __hip_atomic_load(p, __ATOMIC_RELAXED, __HIP_MEMORY_SCOPE_AGENT);
}
__device__ __forceinline__ void agent_st(float* p, float v) {
    __hip_atomic_store(p, v, __ATOMIC_RELAXED, __HIP_MEMORY_SCOPE_AGENT);
}

// Skewed LDS column: +4 floats per 32-float block -> <=2-way bank aliasing
// for both ks*16-strided and ks*8-strided b128 reads (2-way is free, m136).
__device__ __forceinline__ int scol(int k) { return k + ((k >> 5) << 2); }

// VALU cross-lane via DPP (NOT __shfl: that uses the LDS pipe).
template<int CTRL>
__device__ __forceinline__ float dppmov(float x) {
    return __int_as_float(__builtin_amdgcn_update_dpp(
        0, __float_as_int(x), CTRL, 0xF, 0xF, true));
}
// Full sum across each 16-lane row: quad xor1, quad xor2, row_ror:4, row_ror:8.
__device__ __forceinline__ float red16(float x) {
    x += dppmov<0xB1>(x);    // quad_perm {1,0,3,2}
    x += dppmov<0x4E>(x);    // quad_perm {2,3,0,1}
    x += dppmov<0x124>(x);   // row_ror:4
    x += dppmov<0x128>(x);   // row_ror:8
    return x;
}

// Wf = dec_Wih0 @ outW ; bf = dec_Wih0 @ out_b + dec_bih0
__global__ void fuse_wb(const float* __restrict__ Wih0, const float* __restrict__ oW,
                        const float* __restrict__ ob, const float* __restrict__ bih0,
                        float* __restrict__ Wf, float* __restrict__ bf) {
    int idx = blockIdx.x * 256 + threadIdx.x;
    int r = idx >> 8, h = idx & 255;
    const float* wr = Wih0 + (size_t)r * 128;
    float a = 0.f;
    for (int k = 0; k < 128; ++k) a = fmaf(wr[k], oW[(size_t)k * 256 + h], a);
    Wf[idx] = a;
    if (h == 0) {
        float b = 0.f;
        for (int k = 0; k < 128; ++k) b = fmaf(wr[k], ob[k], b);
        bf[r] = b + bih0[r];
    }
}

// Load this thread's register slice: rows g*256+j, cols ks*16..+15 (K=256).
__device__ __forceinline__ void ldw16(float (&w)[3][16], const float* __restrict__ W,
                                      int j, int ks) {
    #pragma unroll
    for (int g = 0; g < 3; ++g) {
        const float* r = W + (size_t)(g * 256 + j) * 256 + ks * 16;
        #pragma unroll
        for (int c = 0; c < 4; ++c) {
            float4 v = *(const float4*)(r + 4 * c);
            w[g][4*c+0] = v.x; w[g][4*c+1] = v.y; w[g][4*c+2] = v.z; w[g][4*c+3] = v.w;
        }
    }
}
// K=128 variant: cols ks*8..+7.
__device__ __forceinline__ void ldw8(float (&w)[3][8], const float* __restrict__ W,
                                     int j, int ks) {
    #pragma unroll
    for (int g = 0; g < 3; ++g) {
        const float* r = W + (size_t)(g * 256 + j) * 128 + ks * 8;
        #pragma unroll
        for (int c = 0; c < 2; ++c) {
            float4 v = *(const float4*)(r + 4 * c);
            w[g][4*c+0] = v.x; w[g][4*c+1] = v.y; w[g][4*c+2] = v.z; w[g][4*c+3] = v.w;
        }
    }
}

// One GRU layer phase. wi (SLI cols) vs i-acts (iR, stride IST);
// wh (16 cols) vs h-acts (hR, stride 292 = h_prev). DPP-reduce, keep s==ks.
template<int SLI, int IST>
__device__ __forceinline__ void gphase(
    const float (&wi)[3][SLI], const float (&wh)[3][16],
    const float* __restrict__ iR, const float* __restrict__ hR,
    const float* __restrict__ hPrev, float* __restrict__ hout,
    float brz0, float brz1, float bni, float bnh, int ks)
{
    float k0 = 0.f, k1 = 0.f, k2 = 0.f, k3 = 0.f;
    for (int s = 0; s < 16; ++s) {
        const float* ir = iR + s * IST;
        float ai0 = 0.f, ai1 = 0.f, ai2 = 0.f;
        #pragma unroll
        for (int c = 0; c < SLI / 4; ++c) {
            float4 v = *(const float4*)(ir + 4 * c);
            ai0 = fmaf(wi[0][4*c+0], v.x, ai0); ai0 = fmaf(wi[0][4*c+1], v.y, ai0);
            ai0 = fmaf(wi[0][4*c+2], v.z, ai0); ai0 = fmaf(wi[0][4*c+3], v.w, ai0);
            ai1 = fmaf(wi[1][4*c+0], v.x, ai1); ai1 = fmaf(wi[1][4*c+1], v.y, ai1);
            ai1 = fmaf(wi[1][4*c+2], v.z, ai1); ai1 = fmaf(wi[1][4*c+3], v.w, ai1);
            ai2 = fmaf(wi[2][4*c+0], v.x, ai2); ai2 = fmaf(wi[2][4*c+1], v.y, ai2);
            ai2 = fmaf(wi[2][4*c+2], v.z, ai2); ai2 = fmaf(wi[2][4*c+3], v.w, ai2);
        }
        const float* hr = hR + s * 292;
        float ah0 = 0.f, ah1 = 0.f, ah2 = 0.f;
        #pragma unroll
        for (int c = 0; c < 4; ++c) {
            float4 v = *(const float4*)(hr + 4 * c);
            ah0 = fmaf(wh[0][4*c+0], v.x, ah0); ah0 = fmaf(wh[0][4*c+1], v.y, ah0);
            ah0 = fmaf(wh[0][4*c+2], v.z, ah0); ah0 = fmaf(wh[0][4*c+3], v.w, ah0);
            ah1 = fmaf(wh[1][4*c+0], v.x, ah1); ah1 = fmaf(wh[1][4*c+1], v.y, ah1);
            ah1 = fmaf(wh[1][4*c+2], v.z, ah1); ah1 = fmaf(wh[1][4*c+3], v.w, ah1);
            ah2 = fmaf(wh[2][4*c+0], v.x, ah2); ah2 = fmaf(wh[2][4*c+1], v.y, ah2);
            ah2 = fmaf(wh[2][4*c+2], v.z, ah2); ah2 = fmaf(wh[2][4*c+3], v.w, ah2);
        }
        float c0 = red16(ai0 + ah0);   // r gate (i+h)
        float c1 = red16(ai1 + ah1);   // z gate
        float c2 = red16(ai2);         // n gate, i part
        float c3 = red16(ah2);         // n gate, h part
        if (s == ks) { k0 = c0; k1 = c1; k2 = c2; k3 = c3; }
    }
    float r = SIGF(k0 + brz0);
    float z = SIGF(k1 + brz1);
    float n = tanhf(k2 + bni + r * (k3 + bnh));
    float hp = *hPrev;
    agent_st(hout, (1.f - z) * n + z * hp);
}

__global__ __launch_bounds__(512, 2) void behav_main(
    const float* __restrict__ pose,
    const float* __restrict__ eW0i, const float* __restrict__ eW0h,
    const float* __restrict__ eb0i, const float* __restrict__ eb0h,
    const float* __restrict__ eW1i, const float* __restrict__ eW1h,
    const float* __restrict__ eb1i, const float* __restrict__ eb1h,
    const float* __restrict__ dW0i, const float* __restrict__ dW0h,
    const float* __restrict__ db0i, const float* __restrict__ db0h,
    const float* __restrict__ dW1i, const float* __restrict__ dW1h,
    const float* __restrict__ db1i, const float* __restrict__ db1h,
    const float* __restrict__ oW, const float* __restrict__ ob,
    float* __restrict__ out,
    float* h0a, float* h0b, float* h1a, float* h1b,
    const float* __restrict__ Wf, const float* __restrict__ bf,
    unsigned* ctrs)
{
    __shared__ float h0ls[16][292];
    __shared__ float h1ls[16][292];
    __shared__ float xls[16][148];
    __shared__ float oWls[16][292];   // (292*3+148)*16*4 = 64 KB exactly

    const int tid = threadIdx.x;
    const int bid = blockIdx.x;
    const int xcd = bid & 7;
    const int inner = bid >> 3;                 // [0,32)
    const int uwg = inner & 7;                  // unit-group [0,8)
    const int c = ((inner >> 3) << 3) | xcd;    // cluster [0,32), XCD-pinned
    const int s0 = c << 4, j0 = uwg << 5;
    const int u = tid >> 4, ks = tid & 15;
    const int j = j0 + u;                       // this thread's unit
    unsigned* ctr = ctrs + (c << 6);
    unsigned epoch = 0;

    float* h0buf[2] = { h0a, h0b };
    float* h1buf[2] = { h1a, h1b };
    int pp = 0;

    const int xbase = scol(ks * 8);
    const int hbase = scol(ks * 16);
    const int pcol  = scol(j);
    const size_t hoff = (size_t)(s0 + ks) * 256 + j;

    auto cbar = [&]() {
        __syncthreads();
        ++epoch;
        if (tid == 0) {
            __hip_atomic_fetch_add(ctr, 1u, __ATOMIC_RELAXED, __HIP_MEMORY_SCOPE_AGENT);
            unsigned tgt = epoch * 8u;
            while (__hip_atomic_load(ctr, __ATOMIC_RELAXED, __HIP_MEMORY_SCOPE_AGENT) < tgt)
                __builtin_amdgcn_s_sleep(1);
        }
        __syncthreads();
    };

    auto stage_x = [&](int t) {
        const int row = tid >> 5, k = (tid & 31) << 2;
        float4 v = *(const float4*)(pose + (size_t)(s0 + row) * 8192 + (size_t)t * 128 + k);
        *(float4*)&xls[row][scol(k)] = v;
    };
    auto stage_h = [&](float (*dst)[292], const float* src) {
        const int row = tid >> 5, k = (tid & 31) << 3;
        const float* s = src + (size_t)(s0 + row) * 256 + k;
        float v0 = agent_ld(s + 0), v1 = agent_ld(s + 1), v2 = agent_ld(s + 2), v3 = agent_ld(s + 3);
        float v4 = agent_ld(s + 4), v5 = agent_ld(s + 5), v6 = agent_ld(s + 6), v7 = agent_ld(s + 7);
        const int d = scol(k);
        *(float4*)&dst[row][d]     = make_float4(v0, v1, v2, v3);
        *(float4*)&dst[row][d + 4] = make_float4(v4, v5, v6, v7);
    };
    // out_t = oW . h1ls + ob  (oW LDS-stationary; DPP reduce over 32 lanes)
    auto do_proj = [&](int t) {
        const int pl = tid >> 6, sh = (tid >> 5) & 1, q = tid & 31;
        const int p0 = (uwg << 4) + pl, p1 = p0 + 8;
        const int wb = scol(q * 8);
        const float* w0 = &oWls[pl][wb];
        const float* w1 = &oWls[pl + 8][wb];
        float4 wa0 = *(const float4*)w0, wa1 = *(const float4*)(w0 + 4);
        float4 wc0 = *(const float4*)w1, wc1 = *(const float4*)(w1 + 4);
        float o0 = ob[p0], o1 = ob[p1];
        for (int i = 0; i < 8; ++i) {
            const int s = (sh << 3) + i;
            const float* hr = &h1ls[s][wb];
            float4 a0 = *(const float4*)hr, a1 = *(const float4*)(hr + 4);
            float acc0 = 0.f, acc1 = 0.f;
            acc0 = fmaf(wa0.x, a0.x, acc0); acc0 = fmaf(wa0.y, a0.y, acc0);
            acc0 = fmaf(wa0.z, a0.z, acc0); acc0 = fmaf(wa0.w, a0.w, acc0);
            acc0 = fmaf(wa1.x, a1.x, acc0); acc0 = fmaf(wa1.y, a1.y, acc0);
            acc0 = fmaf(wa1.z, a1.z, acc0); acc0 = fmaf(wa1.w, a1.w, acc0);
            acc1 = fmaf(wc0.x, a0.x, acc1); acc1 = fmaf(wc0.y, a0.y, acc1);
            acc1 = fmaf(wc0.z, a0.z, acc1); acc1 = fmaf(wc0.w, a0.w, acc1);
            acc1 = fmaf(wc1.x, a1.x, acc1); acc1 = fmaf(wc1.y, a1.y, acc1);
            acc1 = fmaf(wc1.z, a1.z, acc1); acc1 = fmaf(wc1.w, a1.w, acc1);
            acc0 = red16(acc0); acc0 += dppmov<0x142>(acc0);   // row_bcast15
            acc1 = red16(acc1); acc1 += dppmov<0x142>(acc1);
            if (q == 16) {
                size_t base = (size_t)(s0 + s) * 65536 + (size_t)t * 128;
                out[base + p0] = acc0 + o0;
                out[base + p1] = acc1 + o1;
            }
        }
    };

    // Stage oW slice (rows uwg*16..+15) into LDS once.
    {
        const int row = tid >> 5, k = (tid & 31) << 3;
        const float* s = oW + (size_t)((uwg << 4) + row) * 256 + k;
        float4 a = *(const float4*)s, b = *(const float4*)(s + 4);
        const int d = scol(k);
        *(float4*)&oWls[row][d]     = a;
        *(float4*)&oWls[row][d + 4] = b;
    }

    // Register-stationary weight slices (time-multiplexed by era).
    float w8[3][8];                       // K=128 input mat (eW0i, then dW0i)
    float w_h[3][16], v_i[3][16], v_h[3][16], w_i[3][16];
    float b00, b01, b0ni, b0nh, b10, b11, b1ni, b1nh;

    auto ldbias = [&](const float* __restrict__ bi, const float* __restrict__ bh,
                      float& x0, float& x1, float& xni, float& xnh) {
        x0 = bi[j] + bh[j];
        x1 = bi[256 + j] + bh[256 + j];
        xni = bi[512 + j];
        xnh = bh[512 + j];
    };

    // ===================== ENCODER =====================
    ldw8 (w8 , eW0i, j, ks);
    ldw16(w_h, eW0h, j, ks);
    ldw16(v_i, eW1i, j, ks);
    ldw16(v_h, eW1h, j, ks);
    ldbias(eb0i, eb0h, b00, b01, b0ni, b0nh);
    ldbias(eb1i, eb1h, b10, b11, b1ni, b1nh);

    for (int t = 0; t < 64; ++t) {
        stage_x(t);
        stage_h(h0ls, h0buf[pp]);
        __syncthreads();
        gphase<8, 148>(w8, w_h, &xls[0][xbase], &h0ls[0][hbase], &h0ls[ks][pcol],
                       h0buf[pp ^ 1] + hoff, b00, b01, b0ni, b0nh, ks);
        cbar();
        stage_h(h0ls, h0buf[pp ^ 1]);
        stage_h(h1ls, h1buf[pp]);
        __syncthreads();
        gphase<16, 292>(v_i, v_h, &h0ls[0][hbase], &h1ls[0][hbase], &h1ls[ks][pcol],
                        h1buf[pp ^ 1] + hoff, b10, b11, b1ni, b1nh, ks);
        cbar();
        pp ^= 1;
    }

    // ===================== DECODER: teacher (t<64) =====================
    ldw8 (w8 , dW0i, j, ks);
    ldw16(w_h, dW0h, j, ks);
    ldw16(v_i, dW1i, j, ks);
    ldw16(v_h, dW1h, j, ks);
    ldbias(db0i, db0h, b00, b01, b0ni, b0nh);
    ldbias(db1i, db1h, b10, b11, b1ni, b1nh);

    for (int t = 0; t < 64; ++t) {
        stage_x(t);
        stage_h(h0ls, h0buf[pp]);
        stage_h(h1ls, h1buf[pp]);
        __syncthreads();
        if (t >= 1) do_proj(t - 1);
        gphase<8, 148>(w8, w_h, &xls[0][xbase], &h0ls[0][hbase], &h0ls[ks][pcol],
                       h0buf[pp ^ 1] + hoff, b00, b01, b0ni, b0nh, ks);
        cbar();
        stage_h(h0ls, h0buf[pp ^ 1]);
        __syncthreads();
        gphase<16, 292>(v_i, v_h, &h0ls[0][hbase], &h1ls[0][hbase], &h1ls[ks][pcol],
                        h1buf[pp ^ 1] + hoff, b10, b11, b1ni, b1nh, ks);
        cbar();
        pp ^= 1;
    }

    // ===================== DECODER: autoregressive =====================
    ldw16(w_i, Wf, j, ks);                 // fused Wih0@outW
    b00  = bf[j] + db0h[j];
    b01  = bf[256 + j] + db0h[256 + j];
    b0ni = bf[512 + j];
    b0nh = db0h[512 + j];

    for (int t = 64; t < 512; ++t) {
        stage_h(h0ls, h0buf[pp]);
        stage_h(h1ls, h1buf[pp]);
        __syncthreads();
        do_proj(t - 1);
        gphase<16, 292>(w_i, w_h, &h1ls[0][hbase], &h0ls[0][hbase], &h0ls[ks][pcol],
                        h0buf[pp ^ 1] + hoff, b00, b01, b0ni, b0nh, ks);
        cbar();
        stage_h(h0ls, h0buf[pp ^ 1]);
        __syncthreads();
        gphase<16, 292>(v_i, v_h, &h0ls[0][hbase], &h1ls[0][hbase], &h1ls[ks][pcol],
                        h1buf[pp ^ 1] + hoff, b10, b11, b1ni, b1nh, ks);
        cbar();
        pp ^= 1;
    }

    stage_h(h1ls, h1buf[pp]);
    __syncthreads();
    do_proj(511);
}

extern "C" void kernel_launch(void* const* d_in, const int* in_sizes, int n_in,
                              void* d_out, int out_size, void* d_ws, size_t ws_size,
                              hipStream_t stream) {
    (void)in_sizes; (void)n_in; (void)out_size; (void)ws_size;

    const float* pose = (const float*)d_in[0];
    const float* eW0i = (const float*)d_in[1];
    const float* eW0h = (const float*)d_in[2];
    const float* eb0i = (const float*)d_in[3];
    const float* eb0h = (const float*)d_in[4];
    const float* eW1i = (const float*)d_in[5];
    const float* eW1h = (const float*)d_in[6];
    const float* eb1i = (const float*)d_in[7];
    const float* eb1h = (const float*)d_in[8];
    const float* dW0i = (const float*)d_in[9];
    const float* dW0h = (const float*)d_in[10];
    const float* db0i = (const float*)d_in[11];
    const float* db0h = (const float*)d_in[12];
    const float* dW1i = (const float*)d_in[13];
    const float* dW1h = (const float*)d_in[14];
    const float* db1i = (const float*)d_in[15];
    const float* db1h = (const float*)d_in[16];
    const float* oW   = (const float*)d_in[17];
    const float* ob   = (const float*)d_in[18];

    float* ws = (float*)d_ws;
    float* h0a = ws + OFF_H0A;
    float* h0b = ws + OFF_H0B;
    float* h1a = ws + OFF_H1A;
    float* h1b = ws + OFF_H1B;
    float* Wf  = ws + OFF_WF;
    float* bf  = ws + OFF_BF;
    unsigned* ctrs = (unsigned*)(ws + OFF_CTR);
    float* outf = (float*)d_out;

    hipMemsetAsync(d_ws, 0, 262144 * sizeof(float), stream);   // h0a + h1a = 0
    hipMemsetAsync((void*)ctrs, 0, 32 * 64 * sizeof(unsigned), stream);

    fuse_wb<<<dim3(768), dim3(256), 0, stream>>>(dW0i, oW, ob, db0i, Wf, bf);

    void* kargs[] = {
        (void*)&pose,
        (void*)&eW0i, (void*)&eW0h, (void*)&eb0i, (void*)&eb0h,
        (void*)&eW1i, (void*)&eW1h, (void*)&eb1i, (void*)&eb1h,
        (void*)&dW0i, (void*)&dW0h, (void*)&db0i, (void*)&db0h,
        (void*)&dW1i, (void*)&dW1h, (void*)&db1i, (void*)&db1h,
        (void*)&oW, (void*)&ob,
        (void*)&outf,
        (void*)&h0a, (void*)&h0b, (void*)&h1a, (void*)&h1b,
        (void*)&Wf, (void*)&bf,
        (void*)&ctrs
    };
    hipLaunchCooperativeKernel((const void*)behav_main, dim3(256), dim3(512),
                               kargs, 0, stream);
}

// Round 5
// 9310.673 us; speedup vs baseline: 4.8511x; 1.4375x over previous
//
#include <hip/hip_runtime.h>
#include <cstddef>
#include <cstdint>

// ---------------------------------------------------------------------------
// GRU seq2seq via MFMA, 3-term bf16 split (wh*ah + wh*al + wl*ah).
// 32 clusters x 16 samples; 8 WGs/cluster (32 units = 128 gate-rows each);
// WG = 512 thr = 8 waves. Weights register-stationary (bf16 hi/lo frags),
// K split across waves, cross-wave reduce via LDS partials. XCD-pinned
// clusters, fence-free L2 barrier, coop 256x512 (proven shape).
// Tiles per phase: r(2) z(2) n_i(2) n_h(2) + proj(1, phase-2, decoder).
// ---------------------------------------------------------------------------

typedef __attribute__((ext_vector_type(8))) short short8v;
typedef __attribute__((ext_vector_type(4))) float float4v;

static const size_t OFF_H0A = 0;                    // 512*256
static const size_t OFF_H1A = 131072;
static const size_t OFF_H0B = 262144;
static const size_t OFF_H1B = 393216;
static const size_t OFF_WF  = 524288;               // 768*256
static const size_t OFF_BF  = OFF_WF + 196608;      // 768 (pad 1024)
static const size_t OFF_CTR = OFF_BF + 1024;        // 32*64 uints

#define SIGF(x) (1.0f / (1.0f + __expf(-(x))))
#define MFMA16 __builtin_amdgcn_mfma_f32_16x16x32_bf16
#define MM3(C, WH, WL, BH, BL) \
    C = MFMA16(WH, BH, C, 0, 0, 0); \
    C = MFMA16(WH, BL, C, 0, 0, 0); \
    C = MFMA16(WL, BH, C, 0, 0, 0);

__device__ __forceinline__ float agent_ld(const float* p) {
    return __hip_atomic_load(p, __ATOMIC_RELAXED, __HIP_MEMORY_SCOPE_AGENT);
}
__device__ __forceinline__ void agent_st(float* p, float v) {
    __hip_atomic_store(p, v, __ATOMIC_RELAXED, __HIP_MEMORY_SCOPE_AGENT);
}
__device__ __forceinline__ unsigned short f2bf(float x) {
    unsigned u = __float_as_uint(x);
    return (unsigned short)((u + 0x7FFFu + ((u >> 16) & 1u)) >> 16);
}
__device__ __forceinline__ float bf2f(unsigned short h) {
    return __uint_as_float(((unsigned)h) << 16);
}

// Wf = dec_Wih0 @ outW ; bf = dec_Wih0 @ out_b + dec_bih0
__global__ void fuse_wb(const float* __restrict__ Wih0, const float* __restrict__ oW,
                        const float* __restrict__ ob, const float* __restrict__ bih0,
                        float* __restrict__ Wf, float* __restrict__ bf) {
    int idx = blockIdx.x * 256 + threadIdx.x;
    int r = idx >> 8, h = idx & 255;
    const float* wr = Wih0 + (size_t)r * 128;
    float a = 0.f;
    for (int k = 0; k < 128; ++k) a = fmaf(wr[k], oW[(size_t)k * 256 + h], a);
    Wf[idx] = a;
    if (h == 0) {
        float b = 0.f;
        for (int k = 0; k < 128; ++k) b = fmaf(wr[k], ob[k], b);
        bf[r] = b + bih0[r];
    }
}

__global__ __launch_bounds__(512, 2) void behav_main(
    const float* __restrict__ pose,
    const float* __restrict__ eW0i, const float* __restrict__ eW0h,
    const float* __restrict__ eb0i, const float* __restrict__ eb0h,
    const float* __restrict__ eW1i, const float* __restrict__ eW1h,
    const float* __restrict__ eb1i, const float* __restrict__ eb1h,
    const float* __restrict__ dW0i, const float* __restrict__ dW0h,
    const float* __restrict__ db0i, const float* __restrict__ db0h,
    const float* __restrict__ dW1i, const float* __restrict__ dW1h,
    const float* __restrict__ db1i, const float* __restrict__ db1h,
    const float* __restrict__ oW, const float* __restrict__ ob,
    float* __restrict__ out,
    float* h0a, float* h0b, float* h1a, float* h1b,
    const float* __restrict__ Wf, const float* __restrict__ bf,
    unsigned* ctrs)
{
    // SLOT_A: h1_prev (x-role in AR);  SLOT_B: h0_prev -> h0_new
    __shared__ short Ah[16][264];     // 528B rows: 16B-aligned, conflict-free
    __shared__ short Al[16][264];
    __shared__ short Bh[16][264];
    __shared__ short Bl[16][264];
    __shared__ float4v P[16][64];     // partials: [w*2+slot][lane]
    __shared__ float4v G[9][64];      // reduced gates + proj

    const int tid = threadIdx.x;
    const int lane = tid & 63;
    const int w = tid >> 6;
    const int bid = blockIdx.x;
    const int xcd = bid & 7;
    const int inner = bid >> 3;
    const int uwg = inner & 7;
    const int c = ((inner >> 3) << 3) | xcd;    // XCD-pinned cluster
    const int s0 = c << 4, j0 = uwg << 5;
    unsigned* ctr = ctrs + (c << 6);
    unsigned epoch = 0;
    float* Gf = (float*)&G[0][0];

    float* h0buf[2] = { h0a, h0b };
    float* h1buf[2] = { h1a, h1b };
    int pp = 0;

    const size_t hoff = (size_t)(s0 + (tid >> 5)) * 256 + j0 + (tid & 31);
    const float4v FZ = {0.f, 0.f, 0.f, 0.f};

    auto cbar = [&]() {
        __syncthreads();
        ++epoch;
        if (tid == 0) {
            __hip_atomic_fetch_add(ctr, 1u, __ATOMIC_RELAXED, __HIP_MEMORY_SCOPE_AGENT);
            unsigned tgt = epoch * 8u;
            while (__hip_atomic_load(ctr, __ATOMIC_RELAXED, __HIP_MEMORY_SCOPE_AGENT) < tgt)
                __builtin_amdgcn_s_sleep(1);
        }
        __syncthreads();
    };

    auto cvt8 = [&](const float* p, short8v& hv, short8v& lv) {
        float4 a = *(const float4*)p;
        float4 b = *(const float4*)(p + 4);
        float vv[8] = {a.x, a.y, a.z, a.w, b.x, b.y, b.z, b.w};
        #pragma unroll
        for (int i = 0; i < 8; ++i) {
            unsigned short h = f2bf(vv[i]);
            hv[i] = (short)h;
            lv[i] = (short)f2bf(vv[i] - bf2f(h));
        }
    };
    // A-frag: lane holds W[row0 + (lane&15)][col0 + (lane>>4)*8 .. +7]
    auto ldfrag = [&](const float* M, int ldm, int row0, int col0, short8v& hv, short8v& lv) {
        const float* p = M + (size_t)(row0 + (lane & 15)) * ldm + col0 + ((lane >> 4) << 3);
        cvt8(p, hv, lv);
    };
    // B-frag: lane holds Act[lane&15][kloc*32 + (lane>>4)*8 .. +7]
    auto rdB = [&](const short (*arr)[264], int kloc) -> short8v {
        return *(const short8v*)&arr[lane & 15][(kloc << 5) + ((lane >> 4) << 3)];
    };
    auto rdX = [&](int t, int loc, short8v& hv, short8v& lv) {
        const float* p = pose + (size_t)(s0 + (lane & 15)) * 8192 + (size_t)t * 128
                         + (loc << 5) + ((lane >> 4) << 3);
        cvt8(p, hv, lv);
    };
    auto stage = [&](short (*ha)[264], short (*la)[264], const float* src) {
        int s = tid >> 5, k0 = (tid & 31) << 3;
        const float* p = src + (size_t)(s0 + s) * 256 + k0;
        short8v hv, lv;
        #pragma unroll
        for (int i = 0; i < 8; ++i) {
            float x = agent_ld(p + i);
            unsigned short h = f2bf(x);
            hv[i] = (short)h;
            lv[i] = (short)f2bf(x - bf2f(h));
        }
        *(short8v*)&ha[s][k0] = hv;
        *(short8v*)&la[s][k0] = lv;
    };
    auto getG = [&](int lr, int s) -> float {
        return Gf[((lr >> 4) << 8) + ((s + (((lr & 15) >> 2) << 4)) << 2) + (lr & 3)];
    };

    // ---------------- weight fragments (register-stationary) ----------------
    short8v W1fh[4][2], W1fl[4][2], W1nh[2][2], W1nl[2][2];
    short8v W2fh[4][2], W2fl[4][2], W2nh[2][2], W2nl[2][2];
    short8v PJh, PJl;
    float b0r, b0z, b0ni, b0nh, b1r, b1z, b1ni, b1nh;
    const float obv = ((tid & 31) < 16) ? ob[(uwg << 4) + (tid & 31)] : 0.f;

    int p1_nks, p1_src[2], p1_loc[2], p1_isI[2];   // src: 0=SLOT_A 1=SLOT_B 2=pose
    int p2_loc[2], p2_isI[2];
    {
        int kk0 = w << 1, kk1 = (w << 1) | 1;
        p2_isI[0] = kk0 < 8; p2_loc[0] = p2_isI[0] ? kk0 : kk0 - 8;
        p2_isI[1] = kk1 < 8; p2_loc[1] = p2_isI[1] ? kk1 : kk1 - 8;
    }
    auto set_p1_enclike = [&]() {
        if (w < 4) {
            p1_nks = 2;
            p1_isI[0] = 1; p1_src[0] = 2; p1_loc[0] = w;        // x Kstep w
            p1_isI[1] = 0; p1_src[1] = 1; p1_loc[1] = w;        // h Kstep 4+w
        } else {
            p1_nks = 1;
            p1_isI[0] = 0; p1_src[0] = 1; p1_loc[0] = w;        // h Kstep 4+w (loc 4..7)
            p1_isI[1] = 0; p1_src[1] = 1; p1_loc[1] = 0;
        }
    };
    auto set_p1_ar = [&]() {
        p1_nks = 2;
        int kk0 = w << 1, kk1 = (w << 1) | 1;
        p1_isI[0] = kk0 < 8; p1_src[0] = p1_isI[0] ? 0 : 1; p1_loc[0] = p1_isI[0] ? kk0 : kk0 - 8;
        p1_isI[1] = kk1 < 8; p1_src[1] = p1_isI[1] ? 0 : 1; p1_loc[1] = p1_isI[1] ? kk1 : kk1 - 8;
    };
    auto load_w1 = [&](const float* Wi, int ldi, const float* Wh) {
        #pragma unroll
        for (int ks = 0; ks < 2; ++ks) {
            if (ks < p1_nks) {
                const float* M = p1_isI[ks] ? Wi : Wh;
                int ld = p1_isI[ks] ? ldi : 256;
                int col = p1_loc[ks] << 5;
                ldfrag(M, ld, j0,           col, W1fh[0][ks], W1fl[0][ks]);
                ldfrag(M, ld, j0 + 16,      col, W1fh[1][ks], W1fl[1][ks]);
                ldfrag(M, ld, 256 + j0,     col, W1fh[2][ks], W1fl[2][ks]);
                ldfrag(M, ld, 256 + j0 + 16, col, W1fh[3][ks], W1fl[3][ks]);
                ldfrag(M, ld, 512 + j0,     col, W1nh[0][ks], W1nl[0][ks]);
                ldfrag(M, ld, 512 + j0 + 16, col, W1nh[1][ks], W1nl[1][ks]);
            }
        }
    };
    auto load_w2 = [&](const float* Wi, const float* Wh) {
        #pragma unroll
        for (int ks = 0; ks < 2; ++ks) {
            const float* M = p2_isI[ks] ? Wi : Wh;
            int col = p2_loc[ks] << 5;
            ldfrag(M, 256, j0,            col, W2fh[0][ks], W2fl[0][ks]);
            ldfrag(M, 256, j0 + 16,       col, W2fh[1][ks], W2fl[1][ks]);
            ldfrag(M, 256, 256 + j0,      col, W2fh[2][ks], W2fl[2][ks]);
            ldfrag(M, 256, 256 + j0 + 16, col, W2fh[3][ks], W2fl[3][ks]);
            ldfrag(M, 256, 512 + j0,      col, W2nh[0][ks], W2nl[0][ks]);
            ldfrag(M, 256, 512 + j0 + 16, col, W2nh[1][ks], W2nl[1][ks]);
        }
    };
    auto ldb = [&](const float* bi, const float* bhh, float& r, float& z, float& ni, float& nh) {
        int jj = j0 + (tid & 31);
        r = bi[jj] + bhh[jj];
        z = bi[256 + jj] + bhh[256 + jj];
        ni = bi[512 + jj];
        nh = bhh[512 + jj];
    };

    // ---------------- GEMM accumulators ----------------
    float4v Cf0, Cf1, Cf2, Cf3, Cni0, Cni1, Cnh0, Cnh1, Cpj;

    auto gemm_p1 = [&](int t) {
        Cf0 = FZ; Cf1 = FZ; Cf2 = FZ; Cf3 = FZ;
        Cni0 = FZ; Cni1 = FZ; Cnh0 = FZ; Cnh1 = FZ;
        #pragma unroll
        for (int ks = 0; ks < 2; ++ks) {
            if (ks < p1_nks) {
                short8v bh, bl;
                int sr = p1_src[ks], loc = p1_loc[ks];
                if (sr == 2)      rdX(t, loc, bh, bl);
                else if (sr == 1) { bh = rdB(Bh, loc); bl = rdB(Bl, loc); }
                else              { bh = rdB(Ah, loc); bl = rdB(Al, loc); }
                MM3(Cf0, W1fh[0][ks], W1fl[0][ks], bh, bl);
                MM3(Cf1, W1fh[1][ks], W1fl[1][ks], bh, bl);
                MM3(Cf2, W1fh[2][ks], W1fl[2][ks], bh, bl);
                MM3(Cf3, W1fh[3][ks], W1fl[3][ks], bh, bl);
                if (p1_isI[ks]) {
                    MM3(Cni0, W1nh[0][ks], W1nl[0][ks], bh, bl);
                    MM3(Cni1, W1nh[1][ks], W1nl[1][ks], bh, bl);
                } else {
                    MM3(Cnh0, W1nh[0][ks], W1nl[0][ks], bh, bl);
                    MM3(Cnh1, W1nh[1][ks], W1nl[1][ks], bh, bl);
                }
            }
        }
    };
    auto gemm_p2 = [&](bool doproj) {
        Cf0 = FZ; Cf1 = FZ; Cf2 = FZ; Cf3 = FZ;
        Cni0 = FZ; Cni1 = FZ; Cnh0 = FZ; Cnh1 = FZ; Cpj = FZ;
        #pragma unroll
        for (int ks = 0; ks < 2; ++ks) {
            short8v bh, bl;
            if (p2_isI[ks]) { bh = rdB(Bh, p2_loc[ks]); bl = rdB(Bl, p2_loc[ks]); }
            else            { bh = rdB(Ah, p2_loc[ks]); bl = rdB(Al, p2_loc[ks]); }
            MM3(Cf0, W2fh[0][ks], W2fl[0][ks], bh, bl);
            MM3(Cf1, W2fh[1][ks], W2fl[1][ks], bh, bl);
            MM3(Cf2, W2fh[2][ks], W2fl[2][ks], bh, bl);
            MM3(Cf3, W2fh[3][ks], W2fl[3][ks], bh, bl);
            if (p2_isI[ks]) {
                MM3(Cni0, W2nh[0][ks], W2nl[0][ks], bh, bl);
                MM3(Cni1, W2nh[1][ks], W2nl[1][ks], bh, bl);
            } else {
                MM3(Cnh0, W2nh[0][ks], W2nl[0][ks], bh, bl);
                MM3(Cnh1, W2nh[1][ks], W2nl[1][ks], bh, bl);
            }
        }
        if (doproj) {
            short8v bh = rdB(Ah, w), bl = rdB(Al, w);   // proj Kstep 8+w -> SLOT_A loc w
            MM3(Cpj, PJh, PJl, bh, bl);
        }
    };

    // ---------------- reduce / chunks ----------------
    auto redfull = [&](int g0) {
        if (tid < 128) {
            int sl = tid >> 6, l2 = tid & 63;
            float4v a = P[sl][l2] + P[2 + sl][l2] + P[4 + sl][l2] + P[6 + sl][l2]
                      + P[8 + sl][l2] + P[10 + sl][l2] + P[12 + sl][l2] + P[14 + sl][l2];
            G[g0 + sl][l2] = a;
        }
    };
    auto redsplit = [&]() {
        if (tid < 128) {
            int sl = tid >> 6, l2 = tid & 63;
            G[4 + sl][l2] = P[sl][l2] + P[2 + sl][l2] + P[4 + sl][l2] + P[6 + sl][l2];
            G[6 + sl][l2] = P[8 + sl][l2] + P[10 + sl][l2] + P[12 + sl][l2] + P[14 + sl][l2];
        }
    };
    auto chunks_rz = [&]() {
        P[w << 1][lane] = Cf0; P[(w << 1) | 1][lane] = Cf1;
        __syncthreads(); redfull(0); __syncthreads();
        P[w << 1][lane] = Cf2; P[(w << 1) | 1][lane] = Cf3;
        __syncthreads(); redfull(2); __syncthreads();
    };
    auto chunks_n_merged = [&]() {
        P[w << 1][lane]       = (w < 4) ? Cni0 : Cnh0;
        P[(w << 1) | 1][lane] = (w < 4) ? Cni1 : Cnh1;
        __syncthreads(); redsplit(); __syncthreads();
    };
    auto chunks_n_enc = [&]() {   // enc/teacher phase-1: waves may hold both n_i and n_h
        P[w << 1][lane] = Cni0; P[(w << 1) | 1][lane] = Cni1;   // zeros where absent
        __syncthreads(); redfull(4); __syncthreads();
        P[w << 1][lane] = Cnh0; P[(w << 1) | 1][lane] = Cnh1;
        __syncthreads(); redfull(6); __syncthreads();
    };
    auto chunk_proj = [&]() {
        P[w << 1][lane] = Cpj;
        __syncthreads();
        if (tid < 64) {
            G[8][tid] = P[0][tid] + P[2][tid] + P[4][tid] + P[6][tid]
                      + P[8][tid] + P[10][tid] + P[12][tid] + P[14][tid];
        }
        __syncthreads();
    };

    // ---------------- epilogues ----------------
    auto epi_gru = [&](float hp, float* pong, float br, float bz, float bni, float bnh) {
        int s = tid >> 5, ul = tid & 31;
        float r = SIGF(getG(ul, s) + br);
        float z = SIGF(getG(32 + ul, s) + bz);
        float n = tanhf(getG(64 + ul, s) + bni + r * (getG(96 + ul, s) + bnh));
        agent_st(pong + (size_t)(s0 + s) * 256 + j0 + ul, (1.f - z) * n + z * hp);
    };
    auto epi_proj = [&](int tq) {
        int s = tid >> 5, ul = tid & 31;
        if (ul < 16) {
            float v = Gf[(8 << 8) + ((s + ((ul >> 2) << 4)) << 2) + (ul & 3)] + obv;
            out[(size_t)(s0 + s) * 65536 + (size_t)tq * 128 + (uwg << 4) + ul] = v;
        }
    };

    // ---------------- init ----------------
    {
        short8v zz = {0, 0, 0, 0, 0, 0, 0, 0};
        for (int i = tid; i < 528; i += 512) {
            int s = i / 33, k = (i % 33) << 3;
            *(short8v*)&Ah[s][k] = zz;
            *(short8v*)&Al[s][k] = zz;
            *(short8v*)&Bh[s][k] = zz;
            *(short8v*)&Bl[s][k] = zz;
        }
    }
    ldfrag(oW, 256, uwg << 4, w << 5, PJh, PJl);   // proj frag, era-invariant
    __syncthreads();

    // ===================== ENCODER =====================
    set_p1_enclike();
    load_w1(eW0i, 128, eW0h);
    load_w2(eW1i, eW1h);
    ldb(eb0i, eb0h, b0r, b0z, b0ni, b0nh);
    ldb(eb1i, eb1h, b1r, b1z, b1ni, b1nh);

    for (int t = 0; t < 64; ++t) {
        float hp0 = agent_ld(h0buf[pp] + hoff);
        gemm_p1(t);
        chunks_rz(); chunks_n_enc();
        epi_gru(hp0, h0buf[pp ^ 1], b0r, b0z, b0ni, b0nh);
        cbar();
        stage(Bh, Bl, h0buf[pp ^ 1]);
        __syncthreads();
        float hp1 = agent_ld(h1buf[pp] + hoff);
        gemm_p2(false);
        chunks_rz(); chunks_n_merged();
        epi_gru(hp1, h1buf[pp ^ 1], b1r, b1z, b1ni, b1nh);
        cbar();
        stage(Ah, Al, h1buf[pp ^ 1]);
        __syncthreads();
        pp ^= 1;
    }

    // ===================== DECODER =====================
    load_w1(dW0i, 128, dW0h);                     // teacher era (p1 desc unchanged)
    load_w2(dW1i, dW1h);
    ldb(db0i, db0h, b0r, b0z, b0ni, b0nh);
    ldb(db1i, db1h, b1r, b1z, b1ni, b1nh);

    for (int t = 0; t < 512; ++t) {
        if (t == 64) {                             // AR era
            set_p1_ar();
            load_w1(Wf, 256, dW0h);
            int jj = j0 + (tid & 31);
            b0r = bf[jj] + db0h[jj];
            b0z = bf[256 + jj] + db0h[256 + jj];
            b0ni = bf[512 + jj];
            b0nh = db0h[512 + jj];
        }
        const bool ar = (t >= 64);
        const bool dp = (t >= 1);
        float hp0 = agent_ld(h0buf[pp] + hoff);
        gemm_p1(t);
        chunks_rz();
        if (ar) chunks_n_merged(); else chunks_n_enc();
        epi_gru(hp0, h0buf[pp ^ 1], b0r, b0z, b0ni, b0nh);
        cbar();
        stage(Bh, Bl, h0buf[pp ^ 1]);
        __syncthreads();
        float hp1 = agent_ld(h1buf[pp] + hoff);
        gemm_p2(dp);
        chunks_rz(); chunks_n_merged();
        if (dp) chunk_proj();
        epi_gru(hp1, h1buf[pp ^ 1], b1r, b1z, b1ni, b1nh);
        if (dp) epi_proj(t - 1);
        cbar();
        stage(Ah, Al, h1buf[pp ^ 1]);
        __syncthreads();
        pp ^= 1;
    }

    // final projection: out_511 from h1_511 (in SLOT_A)
    {
        Cpj = FZ;
        short8v bh = rdB(Ah, w), bl = rdB(Al, w);
        MM3(Cpj, PJh, PJl, bh, bl);
        chunk_proj();
        epi_proj(511);
    }
}

extern "C" void kernel_launch(void* const* d_in, const int* in_sizes, int n_in,
                              void* d_out, int out_size, void* d_ws, size_t ws_size,
                              hipStream_t stream) {
    (void)in_sizes; (void)n_in; (void)out_size; (void)ws_size;

    const float* pose = (const float*)d_in[0];
    const float* eW0i = (const float*)d_in[1];
    const float* eW0h = (const float*)d_in[2];
    const float* eb0i = (const float*)d_in[3];
    const float* eb0h = (const float*)d_in[4];
    const float* eW1i = (const float*)d_in[5];
    const float* eW1h = (const float*)d_in[6];
    const float* eb1i = (const float*)d_in[7];
    const float* eb1h = (const float*)d_in[8];
    const float* dW0i = (const float*)d_in[9];
    const float* dW0h = (const float*)d_in[10];
    const float* db0i = (const float*)d_in[11];
    const float* db0h = (const float*)d_in[12];
    const float* dW1i = (const float*)d_in[13];
    const float* dW1h = (const float*)d_in[14];
    const float* db1i = (const float*)d_in[15];
    const float* db1h = (const float*)d_in[16];
    const float* oW   = (const float*)d_in[17];
    const float* ob   = (const float*)d_in[18];

    float* ws = (float*)d_ws;
    float* h0a = ws + OFF_H0A;
    float* h0b = ws + OFF_H0B;
    float* h1a = ws + OFF_H1A;
    float* h1b = ws + OFF_H1B;
    float* Wf  = ws + OFF_WF;
    float* bf  = ws + OFF_BF;
    unsigned* ctrs = (unsigned*)(ws + OFF_CTR);
    float* outf = (float*)d_out;

    hipMemsetAsync(d_ws, 0, 262144 * sizeof(float), stream);   // ping h0+h1 = 0
    hipMemsetAsync((void*)ctrs, 0, 32 * 64 * sizeof(unsigned), stream);

    fuse_wb<<<dim3(768), dim3(256), 0, stream>>>(dW0i, oW, ob, db0i, Wf, bf);

    void* kargs[] = {
        (void*)&pose,
        (void*)&eW0i, (void*)&eW0h, (void*)&eb0i, (void*)&eb0h,
        (void*)&eW1i, (void*)&eW1h, (void*)&eb1i, (void*)&eb1h,
        (void*)&dW0i, (void*)&dW0h, (void*)&db0i, (void*)&db0h,
        (void*)&dW1i, (void*)&dW1h, (void*)&db1i, (void*)&db1h,
        (void*)&oW, (void*)&ob,
        (void*)&outf,
        (void*)&h0a, (void*)&h0b, (void*)&h1a, (void*)&h1b,
        (void*)&Wf, (void*)&bf,
        (void*)&ctrs
    };
    hipLaunchCooperativeKernel((const void*)behav_main, dim3(256), dim3(512),
                               kargs, 0, stream);
}